// Round 14
// baseline (101.107 us; speedup 1.0000x reference)
//
#include <hip/hip_runtime.h>
#include <hip/hip_bf16.h>

#define TPB 512
#define PREP_TPB 256

constexpr int B_    = 262144;
constexpr int WIN_  = 5;
constexpr int VOCAB_= 100000;
constexpr int EMB_  = 50;
constexpr int HID_  = 250;
constexpr int OUT_  = 36;
constexpr int KP    = 256;   // padded K for layer 2 (HID 250 -> 256)
constexpr int NP    = 256;   // padded hidden
constexpr int OP    = 48;    // padded out cols (3 x 16)
constexpr int BM    = 128;   // rows per block (halves per-CU wT line traffic)
constexpr int K1    = 320;   // layer-1 K: 5 windows x 64 (each 50 padded to 64)
constexpr int ROWB  = 640;   // x-tile row bytes

constexpr float TWO_LOG2E = 2.8853900817779268f;   // 2*log2(e)

typedef __attribute__((ext_vector_type(8))) short fragA;  // 8 bf16
typedef __attribute__((ext_vector_type(4))) float fragC;  // 4 f32 acc

__device__ __forceinline__ short f2b(float f) {
    __hip_bfloat16 h = __float2bfloat16(f);      // native RNE cvt
    return *reinterpret_cast<short*>(&h);
}

__device__ __forceinline__ unsigned pack2(float x, float y) {
    return (unsigned)(unsigned short)f2b(x) | ((unsigned)(unsigned short)f2b(y) << 16);
}

// tanh(a + bias) with pre-scaled bias b2 = 2*log2e*bias
__device__ __forceinline__ float tanh_b(float a, float b2) {
    float e = __builtin_amdgcn_exp2f(__builtin_fmaf(a, TWO_LOG2E, b2));
    return __builtin_fmaf(-2.f, __builtin_amdgcn_rcpf(e + 1.f), 1.f);
}

// Swizzled x-tile: row stride 640B; XOR byte ^ ((row&7)<<4) -> conflict-free
// 16B reads/writes (R5: 0 conflicts).
__device__ __forceinline__ void* xp(char* xs, int row, int b) {
    return xs + row * ROWB + (b ^ ((row & 7) << 4));
}

// emb_table f32 [VOCAB][50] -> bf16 [VOCAB+1][64]; cols 50..63 zero; row VOCAB_
// all-zero (branch-free target for invalid indices in the DMA gather).
__global__ void prep_emb(const float* __restrict__ emb, short* __restrict__ emb_b) {
    int id = blockIdx.x * PREP_TPB + threadIdx.x;      // one dword (2 cols) each
    if (id >= (VOCAB_ + 1) * 32) return;
    int row = id >> 5, c2 = id & 31;
    unsigned v = 0u;
    if (row < VOCAB_ && c2 < 25) {
        float2 f = *(const float2*)(emb + row * EMB_ + 2 * c2);  // 8B-aligned
        v = pack2(f.x, f.y);
    }
    ((unsigned*)emb_b)[id] = v;
}

// K-BLOCKED weight layouts (R11 coalescing win):
//   wT2 [10][256][32]: wT2[kk][n][j] = W1[k1=kk*32+j (window-padded)][n]
//   woT2 [8][48][32]:  woT2[kk][o][j] = W2[k=kk*32+j][o]
// b_in -> f32[256] pre-scaled by 2*log2e, b_out -> f32[48] zero-padded
__global__ void prep_weights(const float* __restrict__ w_in,
                             const float* __restrict__ w_out,
                             const float* __restrict__ b_in,
                             const float* __restrict__ b_out,
                             short* __restrict__ wT,
                             short* __restrict__ woT,
                             float* __restrict__ b_in_p,
                             float* __restrict__ b_out_p) {
    int id = blockIdx.x * PREP_TPB + threadIdx.x;
    if (id < 10 * NP * 32) {
        int kk = id / (NP * 32), r = id - kk * NP * 32;
        int n = r >> 5, j = r & 31;
        int k1 = kk * 32 + j;
        int w = k1 >> 6, e = k1 & 63;                  // window, elem-in-window
        float v = (n < HID_ && e < EMB_) ? w_in[(w * EMB_ + e) * HID_ + n] : 0.f;
        wT[id] = f2b(v);
        return;
    }
    int id2 = id - 10 * NP * 32;
    if (id2 < 8 * OP * 32) {
        int kk = id2 / (OP * 32), r = id2 - kk * OP * 32;
        int o = r >> 5, j = r & 31;
        int k = kk * 32 + j;
        float v = (o < OUT_ && k < HID_) ? w_out[k * OUT_ + o] : 0.f;
        woT[id2] = f2b(v);
        return;
    }
    int id3 = id2 - 8 * OP * 32;
    if (id3 < NP) { b_in_p[id3] = (id3 < HID_) ? b_in[id3] * TWO_LOG2E : 0.f; return; }
    int id4 = id3 - NP;
    if (id4 < OP) { b_out_p[id4] = (id4 < OUT_) ? b_out[id4] : 0.f; }
}

template<bool BF>
__launch_bounds__(TPB, 4)
__global__ void tagger_main(const int* __restrict__ idx,
                            const float* __restrict__ emb,
                            const short* __restrict__ emb_b,
                            const float* __restrict__ b_in_p,
                            const float* __restrict__ b_out_p,
                            const short* __restrict__ wT,
                            const short* __restrict__ woT,
                            float* __restrict__ out) {
    __shared__ char xs[BM * ROWB];     // 81920 B -> 2 blocks/CU (16 waves/CU)

    const int tid   = threadIdx.x;
    const int lane  = tid & 63;
    const int wave  = tid >> 6;        // 0..7
    const int wm    = wave >> 2;       // 0..1: M-group (64 rows)
    const int wn    = wave & 3;        // 0..3: N-group (64 n-cols)
    const int l16   = lane & 15;
    const int khalf = lane >> 4;
    const int r0    = blockIdx.x * BM;

    // ---- gather into xs [128 rows][5 win][128B] ----
    if constexpr (BF) {
        // global_load_lds DMA (R12 proven): dest linear (uniform base + lane*16)
        // == swizzled layout iff the SOURCE carries the inverse XOR (T21).
        // win = bs>>7 swizzle-invariant; invalid idx -> zero row emb_b[VOCAB_].
        #pragma unroll
        for (int it = 0; it < 10; ++it) {
            int o    = (it * TPB + tid) * 16;          // linear LDS byte offset
            int row  = o / ROWB;
            int bs   = o - row * ROWB;                 // swizzled byte in row
            int win  = bs >> 7;
            int boff = (bs & 127) ^ ((row & 7) << 4);  // logical byte in window
            int iv   = idx[(r0 + row) * WIN_ + win];
            unsigned safe = ((unsigned)iv < (unsigned)VOCAB_) ? (unsigned)iv : (unsigned)VOCAB_;
            const short* src = emb_b + (size_t)safe * 64 + (boff >> 1);
            __builtin_amdgcn_global_load_lds(
                (const __attribute__((address_space(1))) unsigned int*)src,
                (__attribute__((address_space(3))) unsigned int*)(xs + it * (TPB * 16) + wave * 1024),
                16, 0, 0);
        }
    } else {
        const int sub = tid & 3;
        #pragma unroll
        for (int it = 0; it < 5; ++it) {
            int p = it * 128 + (tid >> 2);             // (row,win) pair 0..639
            int row = p / 5, win = p - row * 5;
            int iv  = idx[r0 * WIN_ + p];
            bool valid = (iv >= 0 && iv < VOCAB_);
            const float* base = emb + (valid ? iv : 0) * EMB_;
            #pragma unroll
            for (int j = 0; j < 7; ++j) {
                int ch = sub + 4 * j;
                if (ch < 25) {
                    float2 v = make_float2(0.f, 0.f);
                    if (valid) v = *(const float2*)(base + 2 * ch);
                    *(unsigned*)xp(xs, row, win * 128 + 4 * ch) = pack2(v.x, v.y);
                }
            }
            for (int ch = 25 + sub; ch < 32; ch += 4)   // zero pad cols 50..63
                *(unsigned*)xp(xs, row, win * 128 + 4 * ch) = 0u;
        }
    }
    __syncthreads();   // drains vmcnt(0) -> DMA complete

    // ---- layer 1: swapped operands -> D[n][batch]; wave (wm,wn) = 64 rows x 64 n.
    fragC acc[4][4];
    #pragma unroll
    for (int mf = 0; mf < 4; ++mf)
        #pragma unroll
        for (int nf = 0; nf < 4; ++nf)
            acc[mf][nf] = (fragC){0.f, 0.f, 0.f, 0.f};

    const int nb    = wn * 64;
    const int mbase = wm * 64;
    const short* wbase = wT + (nb + l16) * 32 + khalf * 8;   // + kk*8192 + nf*512

    #pragma unroll 2
    for (int kk = 0; kk < 10; ++kk) {
        fragA a[4], b[4];
        #pragma unroll
        for (int mf = 0; mf < 4; ++mf)
            a[mf] = *(const fragA*)xp(xs, mbase + mf * 16 + l16, kk * 64 + khalf * 16);
        #pragma unroll
        for (int nf = 0; nf < 4; ++nf)
            b[nf] = *(const fragA*)(wbase + kk * (NP * 32) + nf * (16 * 32));
        #pragma unroll
        for (int mf = 0; mf < 4; ++mf)
            #pragma unroll
            for (int nf = 0; nf < 4; ++nf)
                acc[mf][nf] = __builtin_amdgcn_mfma_f32_16x16x32_bf16(b[nf], a[mf], acc[mf][nf], 0, 0, 0);
    }

    __syncthreads();  // all xs (x) reads complete before overwriting with h

    // ---- epilogue 1: thread owns batch row, 4 consecutive n; h -> xs [128][512B] ----
    #pragma unroll
    for (int nf = 0; nf < 4; ++nf) {
        const int n0 = nb + nf * 16 + khalf * 4;
        const float4 bi = *(const float4*)&b_in_p[n0];   // pre-scaled by 2*log2e
        #pragma unroll
        for (int mf = 0; mf < 4; ++mf) {
            const int row = mbase + mf * 16 + l16;
            uint2 v;
            v.x = pack2(tanh_b(acc[mf][nf][0], bi.x), tanh_b(acc[mf][nf][1], bi.y));
            v.y = pack2(tanh_b(acc[mf][nf][2], bi.z), tanh_b(acc[mf][nf][3], bi.w));
            *(uint2*)(xs + row * 512 + ((2 * n0) ^ ((l16 & 7) << 4))) = v;
        }
    }
    __syncthreads();

    // ---- layer 2: 24 tiles (8 row-groups x 3 col-groups) over 8 waves, 3 each ----
    const short* wobase = woT + l16 * 32 + khalf * 8;

    #pragma unroll
    for (int i = 0; i < 3; ++i) {
        const int t  = wave + 8 * i;       // 0..23
        const int rf = t & 7, of = t >> 3;
        fragC acc2 = (fragC){0.f, 0.f, 0.f, 0.f};
        #pragma unroll 2
        for (int kk = 0; kk < 8; ++kk) {
            const int row = rf * 16 + l16;
            fragA ha = *(const fragA*)(xs + row * 512 + ((kk * 64 + khalf * 16) ^ ((l16 & 7) << 4)));
            fragA wb = *(const fragA*)(wobase + kk * (OP * 32) + of * (16 * 32));
            acc2 = __builtin_amdgcn_mfma_f32_16x16x32_bf16(wb, ha, acc2, 0, 0, 0);
        }
        const int o0 = of * 16 + khalf * 4;
        if (o0 < OUT_) {
            const int row = r0 + rf * 16 + l16;
            const float4 bo = *(const float4*)&b_out_p[o0];
            float4 v;
            v.x = acc2[0] + bo.x;
            v.y = acc2[1] + bo.y;
            v.z = acc2[2] + bo.z;
            v.w = acc2[3] + bo.w;
            *(float4*)&out[row * OUT_ + o0] = v;   // 16B aligned: 144*row + 4*o0
        }
    }
}

extern "C" void kernel_launch(void* const* d_in, const int* in_sizes, int n_in,
                              void* d_out, int out_size, void* d_ws, size_t ws_size,
                              hipStream_t stream) {
    const int*   idx   = (const int*)d_in[0];
    const float* emb   = (const float*)d_in[1];
    const float* w_in  = (const float*)d_in[2];
    const float* b_in  = (const float*)d_in[3];
    const float* w_out = (const float*)d_in[4];
    const float* b_out = (const float*)d_in[5];
    float* out = (float*)d_out;

    const size_t emb_b_elems = (size_t)(VOCAB_ + 1) * 64;           // 12.8 MB
    const size_t tail_elems  = (size_t)10 * NP * 32 + 8 * OP * 32 + 2 * (NP + OP);
    const size_t need_bf = (emb_b_elems + tail_elems + 256) * 2;
    const bool bf = (ws_size >= need_bf);

    short* emb_b = nullptr;
    short* wT;
    if (bf) {
        emb_b = (short*)d_ws;
        wT    = emb_b + emb_b_elems;
        prep_emb<<<((VOCAB_ + 1) * 32 + PREP_TPB - 1) / PREP_TPB, PREP_TPB, 0, stream>>>(emb, emb_b);
    } else {
        wT = (short*)d_ws;
    }
    short* woT = wT + 10 * NP * 32;
    float* b_in_p  = (float*)(woT + 8 * OP * 32);
    float* b_out_p = b_in_p + NP;

    int prep_threads = 10 * NP * 32 + 8 * OP * 32 + NP + OP;
    prep_weights<<<(prep_threads + PREP_TPB - 1) / PREP_TPB, PREP_TPB, 0, stream>>>(
        w_in, w_out, b_in, b_out, wT, woT, b_in_p, b_out_p);

    if (bf)
        tagger_main<true><<<B_ / BM, TPB, 0, stream>>>(idx, emb, emb_b, b_in_p, b_out_p, wT, woT, out);
    else
        tagger_main<false><<<B_ / BM, TPB, 0, stream>>>(idx, emb, emb_b, b_in_p, b_out_p, wT, woT, out);
}

// Round 15
// 91.668 us; speedup vs baseline: 1.1030x; 1.1030x over previous
//
#include <hip/hip_runtime.h>
#include <hip/hip_bf16.h>

#define TPB 256
#define PREP_TPB 256

constexpr int B_    = 262144;
constexpr int WIN_  = 5;
constexpr int VOCAB_= 100000;
constexpr int EMB_  = 50;
constexpr int HID_  = 250;
constexpr int OUT_  = 36;
constexpr int KP    = 256;   // padded K for layer 2 (HID 250 -> 256)
constexpr int NP    = 256;   // padded hidden
constexpr int OP    = 48;    // padded out cols (3 x 16)
constexpr int BM    = 64;    // rows per block

constexpr float TWO_LOG2E = 2.8853900817779268f;   // 2*log2(e)

typedef __attribute__((ext_vector_type(8))) short fragA;  // 8 bf16
typedef __attribute__((ext_vector_type(4))) float fragC;  // 4 f32 acc

__device__ __forceinline__ short f2b(float f) {
    __hip_bfloat16 h = __float2bfloat16(f);      // native RNE cvt
    return *reinterpret_cast<short*>(&h);
}

__device__ __forceinline__ unsigned pack2(float x, float y) {
    return (unsigned)(unsigned short)f2b(x) | ((unsigned)(unsigned short)f2b(y) << 16);
}

// tanh(a + bias) with pre-scaled bias b2 = 2*log2e*bias
__device__ __forceinline__ float tanh_b(float a, float b2) {
    float e = __builtin_amdgcn_exp2f(__builtin_fmaf(a, TWO_LOG2E, b2));
    return __builtin_fmaf(-2.f, __builtin_amdgcn_rcpf(e + 1.f), 1.f);
}

// emb_table f32 [VOCAB][50] -> bf16 [VOCAB+1][64]; cols 50..63 zero; row VOCAB_
// all-zero (branch-free target for invalid indices in the DMA gather).
__global__ void prep_emb(const float* __restrict__ emb, short* __restrict__ emb_b) {
    int id = blockIdx.x * PREP_TPB + threadIdx.x;      // one dword (2 cols) each
    if (id >= (VOCAB_ + 1) * 32) return;
    int row = id >> 5, c2 = id & 31;
    unsigned v = 0u;
    if (row < VOCAB_ && c2 < 25) {
        float2 f = *(const float2*)(emb + row * EMB_ + 2 * c2);  // 8B-aligned
        v = pack2(f.x, f.y);
    }
    ((unsigned*)emb_b)[id] = v;
}

// K-BLOCKED weight layouts (R11 coalescing win):
//   wT2 [10][256][32]: wT2[kk][n][j] = W1[k1=kk*32+j (window-padded)][n]
//   woT2 [8][48][32]:  woT2[kk][o][j] = W2[k=kk*32+j][o]
// b_in -> f32[256] pre-scaled by 2*log2e, b_out -> f32[48] zero-padded
__global__ void prep_weights(const float* __restrict__ w_in,
                             const float* __restrict__ w_out,
                             const float* __restrict__ b_in,
                             const float* __restrict__ b_out,
                             short* __restrict__ wT,
                             short* __restrict__ woT,
                             float* __restrict__ b_in_p,
                             float* __restrict__ b_out_p) {
    int id = blockIdx.x * PREP_TPB + threadIdx.x;
    if (id < 10 * NP * 32) {
        int kk = id / (NP * 32), r = id - kk * NP * 32;
        int n = r >> 5, j = r & 31;
        int k1 = kk * 32 + j;
        int w = k1 >> 6, e = k1 & 63;                  // window, elem-in-window
        float v = (n < HID_ && e < EMB_) ? w_in[(w * EMB_ + e) * HID_ + n] : 0.f;
        wT[id] = f2b(v);
        return;
    }
    int id2 = id - 10 * NP * 32;
    if (id2 < 8 * OP * 32) {
        int kk = id2 / (OP * 32), r = id2 - kk * OP * 32;
        int o = r >> 5, j = r & 31;
        int k = kk * 32 + j;
        float v = (o < OUT_ && k < HID_) ? w_out[k * OUT_ + o] : 0.f;
        woT[id2] = f2b(v);
        return;
    }
    int id3 = id2 - 8 * OP * 32;
    if (id3 < NP) { b_in_p[id3] = (id3 < HID_) ? b_in[id3] * TWO_LOG2E : 0.f; return; }
    int id4 = id3 - NP;
    if (id4 < OP) { b_out_p[id4] = (id4 < OUT_) ? b_out[id4] : 0.f; }
}

template<bool BF>
__launch_bounds__(TPB, 4)
__global__ void tagger_main(const int* __restrict__ idx,
                            const float* __restrict__ emb,
                            const short* __restrict__ emb_b,
                            const float* __restrict__ b_in_p,
                            const float* __restrict__ b_out_p,
                            const short* __restrict__ wT,
                            const short* __restrict__ woT,
                            float* __restrict__ out) {
    __shared__ char xs[40960];         // x: [5 win][64 rows][128B]; later h: [64][512B]

    const int tid   = threadIdx.x;
    const int lane  = tid & 63;
    const int wave  = tid >> 6;        // 0..3
    const int l16   = lane & 15;
    const int khalf = lane >> 4;
    const int r0    = blockIdx.x * BM;

    // ---- gather into win-major xs: affine indexing (no div), DMA dest linear ----
    if constexpr (BF) {
        #pragma unroll
        for (int it = 0; it < 10; ++it) {
            const int win = it >> 1;                       // compile-time
            const int row = (it & 1) * 32 + (tid >> 3);    // affine in tid
            const int sub = tid & 7;
            int iv = idx[(r0 + row) * WIN_ + win];
            unsigned safe = ((unsigned)iv < (unsigned)VOCAB_) ? (unsigned)iv : (unsigned)VOCAB_;
            // source carries the inverse XOR (T21); dest is linear:
            // win*8192 + (it&1)*4096 + wave*1024 + lane*16
            const short* src = emb_b + (size_t)safe * 64 +
                               ((((unsigned)sub * 16) ^ (((unsigned)row & 7) << 4)) >> 1);
            __builtin_amdgcn_global_load_lds(
                (const __attribute__((address_space(1))) unsigned int*)src,
                (__attribute__((address_space(3))) unsigned int*)
                    (xs + win * 8192 + (it & 1) * 4096 + wave * 1024),
                16, 0, 0);
        }
    } else {
        // fallback: stage x f32->bf16 into the win-major layout
        const int sub = tid & 3;
        #pragma unroll
        for (int it = 0; it < 5; ++it) {
            int p = it * 64 + (tid >> 2);
            int row = p / 5, win = p - row * 5;
            int iv  = idx[r0 * WIN_ + p];
            bool valid = (iv >= 0 && iv < VOCAB_);
            const float* base = emb + (valid ? iv : 0) * EMB_;
            char* wrow = xs + win * 8192 + row * 128;
            const int swz = (row & 7) << 4;
            #pragma unroll
            for (int j = 0; j < 7; ++j) {
                int ch = sub + 4 * j;
                if (ch < 25) {
                    float2 v = make_float2(0.f, 0.f);
                    if (valid) v = *(const float2*)(base + 2 * ch);
                    *(unsigned*)(wrow + ((4 * ch) ^ swz)) = pack2(v.x, v.y);
                }
            }
            for (int ch = 25 + sub; ch < 32; ch += 4)
                *(unsigned*)(wrow + ((4 * ch) ^ swz)) = 0u;
        }
    }
    __syncthreads();   // drains vmcnt(0) -> DMA complete

    // ---- layer 1: swapped operands -> D[n][batch]; wave owns 64 rows x 64 n.
    fragC acc[4][4];
    #pragma unroll
    for (int mf = 0; mf < 4; ++mf)
        #pragma unroll
        for (int nf = 0; nf < 4; ++nf)
            acc[mf][nf] = (fragC){0.f, 0.f, 0.f, 0.f};

    const int nb = wave * 64;
    const short* wbase = wT + (nb + l16) * 32 + khalf * 8;   // + kk*8192 + nf*512

    #pragma unroll
    for (int kk = 0; kk < 10; ++kk) {
        const int win = kk >> 1, half = kk & 1;              // compile-time (unrolled)
        fragA a[4], b[4];
        #pragma unroll
        for (int mf = 0; mf < 4; ++mf) {
            const int row = mf * 16 + l16;
            a[mf] = *(const fragA*)(xs + win * 8192 + row * 128 +
                                    ((half * 64 + khalf * 16) ^ ((row & 7) << 4)));
        }
        #pragma unroll
        for (int nf = 0; nf < 4; ++nf)
            b[nf] = *(const fragA*)(wbase + kk * (NP * 32) + nf * (16 * 32));
        __builtin_amdgcn_s_setprio(1);                       // T5: favor MFMA burst
        #pragma unroll
        for (int mf = 0; mf < 4; ++mf)
            #pragma unroll
            for (int nf = 0; nf < 4; ++nf)
                acc[mf][nf] = __builtin_amdgcn_mfma_f32_16x16x32_bf16(b[nf], a[mf], acc[mf][nf], 0, 0, 0);
        __builtin_amdgcn_s_setprio(0);
    }

    __syncthreads();  // all xs (x) reads complete before overwriting with h

    // ---- epilogue 1: thread owns batch row, 4 consecutive n; h -> xs [64][512B] ----
    #pragma unroll
    for (int nf = 0; nf < 4; ++nf) {
        const int n0 = nb + nf * 16 + khalf * 4;
        const float4 bi = *(const float4*)&b_in_p[n0];   // pre-scaled by 2*log2e
        #pragma unroll
        for (int mf = 0; mf < 4; ++mf) {
            const int row = mf * 16 + l16;
            uint2 v;
            v.x = pack2(tanh_b(acc[mf][nf][0], bi.x), tanh_b(acc[mf][nf][1], bi.y));
            v.y = pack2(tanh_b(acc[mf][nf][2], bi.z), tanh_b(acc[mf][nf][3], bi.w));
            *(uint2*)(xs + row * 512 + ((2 * n0) ^ ((row & 7) << 4))) = v;
        }
    }
    __syncthreads();

    // ---- layer 2: [64 x 256] x [256 x 48]; wave owns 16 rows x 48 cols ----
    fragC acc2[3];
    #pragma unroll
    for (int of = 0; of < 3; ++of) acc2[of] = (fragC){0.f, 0.f, 0.f, 0.f};

    const short* wobase = woT + l16 * 32 + khalf * 8;

    #pragma unroll
    for (int kk = 0; kk < 8; ++kk) {
        const int row = wave * 16 + l16;
        fragA ha = *(const fragA*)(xs + row * 512 +
                                   ((kk * 64 + khalf * 16) ^ ((row & 7) << 4)));
        fragA wb[3];
        #pragma unroll
        for (int of = 0; of < 3; ++of)
            wb[of] = *(const fragA*)(wobase + kk * (OP * 32) + of * (16 * 32));
        __builtin_amdgcn_s_setprio(1);
        #pragma unroll
        for (int of = 0; of < 3; ++of)
            acc2[of] = __builtin_amdgcn_mfma_f32_16x16x32_bf16(wb[of], ha, acc2[of], 0, 0, 0);
        __builtin_amdgcn_s_setprio(0);
    }

    // ---- epilogue 2: thread owns row, 4 consecutive o -> float4 store ----
    {
        const int row = r0 + wave * 16 + l16;
        #pragma unroll
        for (int of = 0; of < 3; ++of) {
            const int o0 = of * 16 + khalf * 4;
            if (o0 < OUT_) {
                const float4 bo = *(const float4*)&b_out_p[o0];
                float4 v;
                v.x = acc2[of][0] + bo.x;
                v.y = acc2[of][1] + bo.y;
                v.z = acc2[of][2] + bo.z;
                v.w = acc2[of][3] + bo.w;
                *(float4*)&out[row * OUT_ + o0] = v;   // 16B aligned: 144*row + 4*o0
            }
        }
    }
}

extern "C" void kernel_launch(void* const* d_in, const int* in_sizes, int n_in,
                              void* d_out, int out_size, void* d_ws, size_t ws_size,
                              hipStream_t stream) {
    const int*   idx   = (const int*)d_in[0];
    const float* emb   = (const float*)d_in[1];
    const float* w_in  = (const float*)d_in[2];
    const float* b_in  = (const float*)d_in[3];
    const float* w_out = (const float*)d_in[4];
    const float* b_out = (const float*)d_in[5];
    float* out = (float*)d_out;

    const size_t emb_b_elems = (size_t)(VOCAB_ + 1) * 64;           // 12.8 MB
    const size_t tail_elems  = (size_t)10 * NP * 32 + 8 * OP * 32 + 2 * (NP + OP);
    const size_t need_bf = (emb_b_elems + tail_elems + 256) * 2;
    const bool bf = (ws_size >= need_bf);

    short* emb_b = nullptr;
    short* wT;
    if (bf) {
        emb_b = (short*)d_ws;
        wT    = emb_b + emb_b_elems;
        prep_emb<<<((VOCAB_ + 1) * 32 + PREP_TPB - 1) / PREP_TPB, PREP_TPB, 0, stream>>>(emb, emb_b);
    } else {
        wT = (short*)d_ws;
    }
    short* woT = wT + 10 * NP * 32;
    float* b_in_p  = (float*)(woT + 8 * OP * 32);
    float* b_out_p = b_in_p + NP;

    int prep_threads = 10 * NP * 32 + 8 * OP * 32 + NP + OP;
    prep_weights<<<(prep_threads + PREP_TPB - 1) / PREP_TPB, PREP_TPB, 0, stream>>>(
        w_in, w_out, b_in, b_out, wT, woT, b_in_p, b_out_p);

    if (bf)
        tagger_main<true><<<B_ / BM, TPB, 0, stream>>>(idx, emb, emb_b, b_in_p, b_out_p, wT, woT, out);
    else
        tagger_main<false><<<B_ / BM, TPB, 0, stream>>>(idx, emb, emb_b, b_in_p, b_out_p, wT, woT, out);
}